// Round 4
// baseline (3851.220 us; speedup 1.0000x reference)
//
#include <hip/hip_runtime.h>
#include <math.h>

// G=128, S=32, P=16, D=768, C=256, NH=4, OUT=7; NR = G*P = 2048
#define NG 128
#define NS 32
#define NP 16
#define ND 768
#define NC 256
#define NHD 4
#define NOUT 7
#define NR 2048

typedef unsigned short ushortT;
typedef short bf16x8 __attribute__((ext_vector_type(8)));
typedef float f32x4 __attribute__((ext_vector_type(4)));

__device__ __forceinline__ ushortT f2b(float f) {
    union { float f; unsigned u; } v; v.f = f;
    unsigned r = (v.u + 0x7FFF + ((v.u >> 16) & 1)) >> 16;
    return (ushortT)r;
}
__device__ __forceinline__ float sigf(float v) { return 1.f / (1.f + expf(-v)); }

#define MFMA16(a, b, c) __builtin_amdgcn_mfma_f32_16x16x32_bf16((a), (b), (c), 0, 0, 0)

// ---------------------------------------------------------------------------
// Kernel A: fin(s) + GRU1 + GRU2 + speaker projection, one block per graph.
// 128 blocks x 512 thr (8 waves; wave w owns gru cols w*32..w*32+31).
// Weight stream = unified 32-chunk pipeline (Wih x8, Whh x8, Whh x8, Wus x8),
// depth-2 register prefetch + single LDS buffer (pad 40 => <=2-way conflicts).
// ---------------------------------------------------------------------------
#define STAGE_CHUNK(c_) do {                                                   \
    uint4* rb_ = ((c_) & 1) ? rB : rA;                                         \
    _Pragma("unroll")                                                          \
    for (int i_ = 0; i_ < 6; ++i_) {                                           \
        const int slot_ = i_ * 512 + tid;                                      \
        *(uint4*)&Lb[(slot_ >> 2) * 40 + (slot_ & 3) * 8] = rb_[i_];           \
    }                                                                          \
    __syncthreads();                                                           \
    const int cn_ = (c_) + 2;                                                  \
    if (cn_ < 32) {                                                            \
        const ushortT* src_ =                                                  \
            (cn_ < 8 ? WihB : (cn_ < 24 ? WhhB : WusB)) + (cn_ & 7) * 32;      \
        _Pragma("unroll")                                                      \
        for (int i_ = 0; i_ < 6; ++i_) {                                       \
            const int slot_ = i_ * 512 + tid;                                  \
            rb_[i_] = *(const uint4*)(src_ + (size_t)(slot_ >> 2) * NC +       \
                                      (slot_ & 3) * 8);                        \
        }                                                                      \
    }                                                                          \
} while (0)

__global__ __launch_bounds__(512) void stepA_kernel(
    const float* __restrict__ hbuf, float* __restrict__ hF,
    ushortT* __restrict__ hB, ushortT* __restrict__ hnB,
    ushortT* __restrict__ spkB,
    const ushortT* __restrict__ WihB, const ushortT* __restrict__ WhhB,
    const ushortT* __restrict__ WusB,
    const float* __restrict__ bih, const float* __restrict__ bhh,
    const float* __restrict__ busv,
    const float* __restrict__ att_src, const float* __restrict__ att_dst,
    const float* __restrict__ gat_b, const float* __restrict__ attW,
    const float* __restrict__ attb, const float* __restrict__ clsW,
    const float* __restrict__ clsb, float* __restrict__ outp, int s)
{
    __shared__ short Lb[768 * 40];        // 60 KB staged weight chunk
    __shared__ float m_f[16][264];        // fin output m (f32)
    __shared__ ushortT m_b[16][264];      // m bf16 (pass1 A); later h_nxt bf16
    __shared__ ushortT Ahs[16][264];      // h_old bf16 (pass2 A); later h_run
    __shared__ float es_s[16][4], ed_s[16][4], gate_s[16], pooled_s[256];

    const int g = blockIdx.x, tid = threadIdx.x;
    const int w = tid >> 6, lane = tid & 63;
    const int quad = lane >> 4, l15 = lane & 15;
    const int row0g = g * 16;
    const int ccol0 = w * 32;

    // prefetch chunks 0,1 (Wih) into regs; overlaps with the fin phase below
    uint4 rA[6], rB[6];
    {
        const ushortT* s0 = WihB;
        const ushortT* s1 = WihB + 32;
#pragma unroll
        for (int i = 0; i < 6; ++i) {
            const int slot = i * 512 + tid, row = slot >> 2, kq = (slot & 3) * 8;
            rA[i] = *(const uint4*)(s0 + (size_t)row * NC + kq);
            rB[i] = *(const uint4*)(s1 + (size_t)row * NC + kq);
        }
    }
    // stage h_old bf16 tile
    {
        const int row = tid >> 5, kq = (tid & 31) * 8;
        *(uint4*)&Ahs[row][kq] = *(const uint4*)(hB + (size_t)(row0g + row) * NC + kq);
    }
    // h_old f32 (gate1 blend)
    float hold[2][4];
#pragma unroll
    for (int nf = 0; nf < 2; ++nf)
#pragma unroll
        for (int r = 0; r < 4; ++r)
            hold[nf][r] = hF[(size_t)(row0g + quad * 4 + r) * NC + ccol0 + nf * 16 + l15];

    // ================= fin(s): hbuf -> m (LDS) + outp ====================
    const float* hb = hbuf + (size_t)row0g * (NHD * NC);
    for (int p = w; p < 16; p += 8) {
        const float* row = hb + (size_t)p * (NHD * NC);
        float ss[4] = {0.f, 0.f, 0.f, 0.f}, sd[4] = {0.f, 0.f, 0.f, 0.f};
#pragma unroll
        for (int i = 0; i < 16; ++i) {
            const int col = lane + 64 * i;
            const float v = row[col];
            ss[i >> 2] += v * att_src[col];
            sd[i >> 2] += v * att_dst[col];
        }
        for (int off = 32; off; off >>= 1)
#pragma unroll
            for (int h = 0; h < 4; ++h) {
                ss[h] += __shfl_down(ss[h], off);
                sd[h] += __shfl_down(sd[h], off);
            }
        if (lane == 0)
#pragma unroll
            for (int h = 0; h < 4; ++h) { es_s[p][h] = ss[h]; ed_s[p][h] = sd[h]; }
    }
    __syncthreads();
    {
        const int p = tid >> 5, cb = (tid & 31) * 8;
        float accv[8];
#pragma unroll
        for (int cj = 0; cj < 8; ++cj) accv[cj] = 0.f;
#pragma unroll
        for (int h = 0; h < 4; ++h) {
            float e1 = es_s[0][h] + ed_s[p][h]; e1 = e1 > 0.f ? e1 : 0.2f * e1;
            float e2 = es_s[p][h] + ed_s[p][h]; e2 = e2 > 0.f ? e2 : 0.2f * e2;
            const float mx = fmaxf(e1, e2);
            float w0 = expf(e1 - mx), w1 = expf(e2 - mx);
            const float inv = 1.f / (w0 + w1);
            w0 *= inv; w1 *= inv;
            const float* r0 = hb + h * NC + cb;
            const float* rp = hb + (size_t)p * (NHD * NC) + h * NC + cb;
#pragma unroll
            for (int cj = 0; cj < 8; ++cj) accv[cj] += w0 * r0[cj] + w1 * rp[cj];
        }
#pragma unroll
        for (int cj = 0; cj < 8; ++cj) {
            const float v = accv[cj] * 0.25f + gat_b[cb + cj];
            m_f[p][cb + cj] = v;
            m_b[p][cb + cj] = f2b(v);
        }
    }
    __syncthreads();
    for (int p = w; p < 16; p += 8) {
        float sg = 0.f;
#pragma unroll
        for (int i = 0; i < 4; ++i) { const int c = lane + 64 * i; sg += m_f[p][c] * attW[c]; }
        for (int off = 32; off; off >>= 1) sg += __shfl_down(sg, off);
        if (lane == 0) gate_s[p] = sg + attb[0];
    }
    __syncthreads();
    if (tid < 256) {
        float mx = -1e30f;
#pragma unroll
        for (int p = 0; p < 16; ++p) mx = fmaxf(mx, gate_s[p]);
        float se = 0.f, pc = 0.f;
#pragma unroll
        for (int p = 0; p < 16; ++p) {
            const float e = expf(gate_s[p] - mx);
            se += e; pc += e * m_f[p][tid];
        }
        pooled_s[tid] = pc / se;
    }
    __syncthreads();
    if (w < NOUT) {
        float a = 0.f;
#pragma unroll
        for (int i = 0; i < 4; ++i) {
            const int c = lane + 64 * i;
            a += pooled_s[c] * clsW[w * NC + c];
        }
        for (int off = 32; off; off >>= 1) a += __shfl_down(a, off);
        if (lane == 0) outp[((size_t)g * NS + s) * NOUT + w] = a + clsb[w];
    }

    // ================= pass 1: gi = m @ Wih^T (chunks 0..7) ==============
    f32x4 ai[3][2], ah[3][2];
#pragma unroll
    for (int gt = 0; gt < 3; ++gt)
#pragma unroll
        for (int nf = 0; nf < 2; ++nf) {
            ai[gt][nf] = (f32x4){0.f, 0.f, 0.f, 0.f};
            ah[gt][nf] = (f32x4){0.f, 0.f, 0.f, 0.f};
        }
#pragma unroll
    for (int c = 0; c < 8; ++c) {
        STAGE_CHUNK(c);
        const int kk = c * 32;
        bf16x8 af = *(const bf16x8*)&m_b[l15][kk + quad * 8];
#pragma unroll
        for (int gt = 0; gt < 3; ++gt)
#pragma unroll
            for (int nf = 0; nf < 2; ++nf) {
                bf16x8 bv = *(const bf16x8*)&Lb[(gt * 256 + ccol0 + nf * 16 + l15) * 40 + quad * 8];
                ai[gt][nf] = MFMA16(af, bv, ai[gt][nf]);
            }
        __syncthreads();
    }
    // ================= pass 2: gh = h_old @ Whh^T (chunks 8..15) =========
#pragma unroll
    for (int c = 8; c < 16; ++c) {
        STAGE_CHUNK(c);
        const int kk = (c - 8) * 32;
        bf16x8 af = *(const bf16x8*)&Ahs[l15][kk + quad * 8];
#pragma unroll
        for (int gt = 0; gt < 3; ++gt)
#pragma unroll
            for (int nf = 0; nf < 2; ++nf) {
                bf16x8 bv = *(const bf16x8*)&Lb[(gt * 256 + ccol0 + nf * 16 + l15) * 40 + quad * 8];
                ah[gt][nf] = MFMA16(af, bv, ah[gt][nf]);
            }
        __syncthreads();
    }
    // ================= gate math 1: h_run ================================
    float hreg[2][4];
#pragma unroll
    for (int nf = 0; nf < 2; ++nf) {
        const int c = ccol0 + nf * 16 + l15;
        const float br = bih[c], bz = bih[256 + c], bn = bih[512 + c];
        const float cr = bhh[c], cz = bhh[256 + c], cn = bhh[512 + c];
#pragma unroll
        for (int r = 0; r < 4; ++r) {
            const int row = quad * 4 + r;
            const float rg = sigf(ai[0][nf][r] + br + ah[0][nf][r] + cr);
            const float zg = sigf(ai[1][nf][r] + bz + ah[1][nf][r] + cz);
            const float ng = tanhf(ai[2][nf][r] + bn + rg * (ah[2][nf][r] + cn));
            const float hn = (1.f - zg) * ng + zg * hold[nf][r];
            hreg[nf][r] = hn;
            const size_t idx = (size_t)(row0g + row) * NC + c;
            hF[idx] = hn;
            const ushortT h16 = f2b(hn);
            hB[idx] = h16;
            Ahs[row][c] = h16;   // visible to all after STAGE_CHUNK(16)'s barrier
        }
    }
    // ================= pass 3: gh2 = h_run @ Whh^T (chunks 16..23) =======
    f32x4 a2[3][2];
#pragma unroll
    for (int gt = 0; gt < 3; ++gt)
#pragma unroll
        for (int nf = 0; nf < 2; ++nf) a2[gt][nf] = (f32x4){0.f, 0.f, 0.f, 0.f};
#pragma unroll
    for (int c = 16; c < 24; ++c) {
        STAGE_CHUNK(c);
        const int kk = (c - 16) * 32;
        bf16x8 af = *(const bf16x8*)&Ahs[l15][kk + quad * 8];
#pragma unroll
        for (int gt = 0; gt < 3; ++gt)
#pragma unroll
            for (int nf = 0; nf < 2; ++nf) {
                bf16x8 bv = *(const bf16x8*)&Lb[(gt * 256 + ccol0 + nf * 16 + l15) * 40 + quad * 8];
                a2[gt][nf] = MFMA16(af, bv, a2[gt][nf]);
            }
        __syncthreads();
    }
    // ================= gate math 2: h_nxt ================================
#pragma unroll
    for (int nf = 0; nf < 2; ++nf) {
        const int c = ccol0 + nf * 16 + l15;
        const float br = bih[c], bz = bih[256 + c], bn = bih[512 + c];
        const float cr = bhh[c], cz = bhh[256 + c], cn = bhh[512 + c];
#pragma unroll
        for (int r = 0; r < 4; ++r) {
            const int row = quad * 4 + r;
            const float rg = sigf(br + a2[0][nf][r] + cr);
            const float zg = sigf(bz + a2[1][nf][r] + cz);
            const float ng = tanhf(bn + rg * (a2[2][nf][r] + cn));
            const float hv = (1.f - zg) * ng + zg * hreg[nf][r];
            const ushortT h16 = f2b(hv);
            hnB[(size_t)(row0g + row) * NC + c] = h16;
            m_b[row][c] = h16;   // h_nxt bf16; row0 feeds the speaker pass
        }
    }
    // ===== pass 4: spk_pre = h_nxt[0] @ Wus^T (chunks 24..31, A row0 only)
    f32x4 aspk[3][2];
#pragma unroll
    for (int gt = 0; gt < 3; ++gt)
#pragma unroll
        for (int nf = 0; nf < 2; ++nf) aspk[gt][nf] = (f32x4){0.f, 0.f, 0.f, 0.f};
#pragma unroll
    for (int c = 24; c < 32; ++c) {
        STAGE_CHUNK(c);
        const int kk = (c - 24) * 32;
        bf16x8 af;
        if (l15 == 0) {
            af = *(const bf16x8*)&m_b[0][kk + quad * 8];
        } else {
#pragma unroll
            for (int i = 0; i < 8; ++i) af[i] = 0;
        }
#pragma unroll
        for (int gt = 0; gt < 3; ++gt)
#pragma unroll
            for (int nf = 0; nf < 2; ++nf) {
                bf16x8 bv = *(const bf16x8*)&Lb[(gt * 256 + ccol0 + nf * 16 + l15) * 40 + quad * 8];
                aspk[gt][nf] = MFMA16(af, bv, aspk[gt][nf]);
            }
        __syncthreads();
    }
    if (quad == 0) {
#pragma unroll
        for (int gt = 0; gt < 3; ++gt)
#pragma unroll
            for (int nf = 0; nf < 2; ++nf) {
                const int col = gt * 256 + ccol0 + nf * 16 + l15;
                spkB[(size_t)g * ND + col] = f2b(fmaxf(aspk[gt][nf][0] + busv[col], 0.f));
            }
    }
}

// ---------------------------------------------------------------------------
// Kernel B: main GAT GEMM (hnB@Wcomb+bcomb, non-speaker rows) + speaker
// overwrite GEMM (spkB@gatW, scatter stride 16). 544 blocks x 256 thr.
// ---------------------------------------------------------------------------
__global__ __launch_bounds__(256) void gatovr_kernel(
    const ushortT* __restrict__ hnB, const ushortT* __restrict__ spkB,
    const ushortT* __restrict__ WcombB, const ushortT* __restrict__ gatB,
    const float* __restrict__ bcomb, float* __restrict__ hbuf)
{
    __shared__ short As[64 * 40];
    __shared__ short Bs[64 * 40];
    const int b = blockIdx.x, tid = threadIdx.x;
    const int lane = tid & 63, wid = tid >> 6;
    const int quad = lane >> 4, l15 = lane & 15;
    const int mh = (wid & 1) * 32, nh = (wid >> 1) * 32;
    const int sr = tid >> 2, skq = (tid & 3) * 8;

    const bool ovr = (b >= 512);
    int row0, col0, K;
    const ushortT *A, *Bt;
    if (!ovr) {
        row0 = (b >> 4) * 64; col0 = (b & 15) * 64;
        A = hnB; Bt = WcombB; K = NC;
    } else {
        const int t = b - 512;
        row0 = (t & 1) * 64; col0 = (t >> 1) * 64;
        A = spkB; Bt = gatB; K = ND;
    }
    const ushortT* aptr = A + (size_t)(row0 + sr) * K;
    const ushortT* bptr = Bt + (size_t)(col0 + sr) * K;

    f32x4 acc[2][2];
    for (int i = 0; i < 2; ++i)
        for (int j = 0; j < 2; ++j) acc[i][j] = (f32x4){0.f, 0.f, 0.f, 0.f};

    for (int kk = 0; kk < K; kk += 32) {
        __syncthreads();
        *(uint4*)&As[sr * 40 + skq] = *(const uint4*)(aptr + kk + skq);
        *(uint4*)&Bs[sr * 40 + skq] = *(const uint4*)(bptr + kk + skq);
        __syncthreads();
        bf16x8 af0 = *(const bf16x8*)&As[(mh + l15) * 40 + quad * 8];
        bf16x8 af1 = *(const bf16x8*)&As[(mh + 16 + l15) * 40 + quad * 8];
        bf16x8 bf0 = *(const bf16x8*)&Bs[(nh + l15) * 40 + quad * 8];
        bf16x8 bf1 = *(const bf16x8*)&Bs[(nh + 16 + l15) * 40 + quad * 8];
        acc[0][0] = MFMA16(af0, bf0, acc[0][0]);
        acc[0][1] = MFMA16(af0, bf1, acc[0][1]);
        acc[1][0] = MFMA16(af1, bf0, acc[1][0]);
        acc[1][1] = MFMA16(af1, bf1, acc[1][1]);
    }
#pragma unroll
    for (int mt = 0; mt < 2; ++mt)
#pragma unroll
        for (int nt = 0; nt < 2; ++nt) {
            const int gc = col0 + nh + nt * 16 + l15;
            const float bv = ovr ? 0.f : bcomb[gc];
#pragma unroll
            for (int r = 0; r < 4; ++r) {
                const int gr = row0 + mh + mt * 16 + quad * 4 + r;
                const float v = acc[mt][nt][r] + bv;
                if (ovr) {
                    hbuf[(size_t)(gr * 16) * (NHD * NC) + gc] = v;
                } else if (gr & 15) {
                    hbuf[(size_t)gr * (NHD * NC) + gc] = v;
                }
            }
        }
}

// ---------------------------------------------------------------------------
// Standalone fin (used once for s=31). hbuf fp32 [2048][1024].
// ---------------------------------------------------------------------------
__global__ __launch_bounds__(256) void fin_kernel(
    const float* __restrict__ hbuf, const float* __restrict__ att_src,
    const float* __restrict__ att_dst, const float* __restrict__ gat_b,
    const float* __restrict__ attW, const float* __restrict__ attb,
    const float* __restrict__ clsW, const float* __restrict__ clsb,
    ushortT* __restrict__ mB, float* __restrict__ outp, int s)
{
    const int g = blockIdx.x, tid = threadIdx.x;
    const int lane = tid & 63, wid = tid >> 6;
    __shared__ float es_s[16][4], ed_s[16][4];
    __shared__ float m_s[16][260];
    __shared__ float gate_s[16];
    __shared__ float pooled_s[256];
    const float* hb = hbuf + (size_t)g * NP * (NHD * NC);

    for (int pi = 0; pi < 4; ++pi) {
        const int p = wid * 4 + pi;
        const float* row = hb + p * (NHD * NC);
        float ss[4] = {0.f, 0.f, 0.f, 0.f}, sd[4] = {0.f, 0.f, 0.f, 0.f};
#pragma unroll
        for (int i = 0; i < 16; ++i) {
            const int col = lane + 64 * i;
            const float v = row[col];
            ss[i >> 2] += v * att_src[col];
            sd[i >> 2] += v * att_dst[col];
        }
        for (int off = 32; off; off >>= 1)
#pragma unroll
            for (int h = 0; h < 4; ++h) {
                ss[h] += __shfl_down(ss[h], off);
                sd[h] += __shfl_down(sd[h], off);
            }
        if (lane == 0)
#pragma unroll
            for (int h = 0; h < 4; ++h) { es_s[p][h] = ss[h]; ed_s[p][h] = sd[h]; }
    }
    __syncthreads();
    {
        const int p = tid >> 4, cb = (tid & 15) * 16;
        float accv[16];
#pragma unroll
        for (int cj = 0; cj < 16; ++cj) accv[cj] = 0.f;
#pragma unroll
        for (int h = 0; h < 4; ++h) {
            float e1 = es_s[0][h] + ed_s[p][h]; e1 = e1 > 0.f ? e1 : 0.2f * e1;
            float e2 = es_s[p][h] + ed_s[p][h]; e2 = e2 > 0.f ? e2 : 0.2f * e2;
            const float mx = fmaxf(e1, e2);
            float w0 = expf(e1 - mx), w1 = expf(e2 - mx);
            const float inv = 1.f / (w0 + w1);
            w0 *= inv; w1 *= inv;
            const float* r0 = hb + h * NC + cb;
            const float* rp = hb + p * (NHD * NC) + h * NC + cb;
#pragma unroll
            for (int cj = 0; cj < 16; ++cj) accv[cj] += w0 * r0[cj] + w1 * rp[cj];
        }
#pragma unroll
        for (int cj = 0; cj < 16; ++cj) {
            const float v = accv[cj] * 0.25f + gat_b[cb + cj];
            m_s[p][cb + cj] = v;
            mB[(size_t)(g * NP + p) * NC + cb + cj] = f2b(v);
        }
    }
    __syncthreads();
    for (int pi = 0; pi < 4; ++pi) {
        const int p = wid * 4 + pi;
        float sg = 0.f;
#pragma unroll
        for (int i = 0; i < 4; ++i) { const int c = lane + 64 * i; sg += m_s[p][c] * attW[c]; }
        for (int off = 32; off; off >>= 1) sg += __shfl_down(sg, off);
        if (lane == 0) gate_s[p] = sg + attb[0];
    }
    __syncthreads();
    float mx = -1e30f;
#pragma unroll
    for (int p = 0; p < 16; ++p) mx = fmaxf(mx, gate_s[p]);
    float ge[16], ssum = 0.f;
#pragma unroll
    for (int p = 0; p < 16; ++p) { ge[p] = expf(gate_s[p] - mx); ssum += ge[p]; }
    const float inv = 1.f / ssum;
    {
        float pc = 0.f;
#pragma unroll
        for (int p = 0; p < 16; ++p) pc += ge[p] * m_s[p][tid];
        pooled_s[tid] = pc * inv;
    }
    __syncthreads();
    const int o = tid >> 5, l32 = tid & 31;
    if (o < NOUT) {
        float a = 0.f;
#pragma unroll
        for (int i = 0; i < 8; ++i) {
            const int c = l32 + 32 * i;
            a += pooled_s[c] * clsW[o * NC + c];
        }
        for (int off = 16; off; off >>= 1) a += __shfl_down(a, off);
        if (l32 == 0) outp[((size_t)g * NS + s) * NOUT + o] = a + clsb[o];
    }
}

// ---------------------------------------------------------------------------
// Generic bf16 MFMA GEMM (prep Wcomb + step 0). 64x64 tile, 256 thr.
// ---------------------------------------------------------------------------
__global__ __launch_bounds__(256) void bgemm_kernel(
    const ushortT* __restrict__ A, const ushortT* __restrict__ Bt,
    const float* __restrict__ bias, float* __restrict__ outF,
    ushortT* __restrict__ outH, int N, int K, int act)
{
    __shared__ short As[64 * 40];
    __shared__ short Bs[64 * 40];
    const int tid = threadIdx.x;
    const int lane = tid & 63, wid = tid >> 6;
    const int quad = lane >> 4, l15 = lane & 15;
    const int row0 = blockIdx.y * 64, col0 = blockIdx.x * 64;
    const int mh = (wid & 1) * 32, nh = (wid >> 1) * 32;
    const int sr = tid >> 2, skq = (tid & 3) * 8;
    const ushortT* aptr = A + (size_t)(row0 + sr) * K;
    const ushortT* bptr = Bt + (size_t)(col0 + sr) * K;

    f32x4 acc[2][2];
    for (int i = 0; i < 2; ++i)
        for (int j = 0; j < 2; ++j) acc[i][j] = (f32x4){0.f, 0.f, 0.f, 0.f};

    for (int kk = 0; kk < K; kk += 32) {
        __syncthreads();
        *(uint4*)&As[sr * 40 + skq] = *(const uint4*)(aptr + kk + skq);
        *(uint4*)&Bs[sr * 40 + skq] = *(const uint4*)(bptr + kk + skq);
        __syncthreads();
        bf16x8 af0 = *(const bf16x8*)&As[(mh + l15) * 40 + quad * 8];
        bf16x8 af1 = *(const bf16x8*)&As[(mh + 16 + l15) * 40 + quad * 8];
        bf16x8 bf0 = *(const bf16x8*)&Bs[(nh + l15) * 40 + quad * 8];
        bf16x8 bf1 = *(const bf16x8*)&Bs[(nh + 16 + l15) * 40 + quad * 8];
        acc[0][0] = MFMA16(af0, bf0, acc[0][0]);
        acc[0][1] = MFMA16(af0, bf1, acc[0][1]);
        acc[1][0] = MFMA16(af1, bf0, acc[1][0]);
        acc[1][1] = MFMA16(af1, bf1, acc[1][1]);
    }
#pragma unroll
    for (int mt = 0; mt < 2; ++mt)
#pragma unroll
        for (int nt = 0; nt < 2; ++nt) {
            const int gc = col0 + nh + nt * 16 + l15;
            const float bv = bias ? bias[gc] : 0.f;
#pragma unroll
            for (int r = 0; r < 4; ++r) {
                const int gr = row0 + mh + mt * 16 + quad * 4 + r;
                float v = acc[mt][nt][r] + bv;
                if (act) v = fmaxf(v, 0.f);
                if (outF) outF[(size_t)gr * N + gc] = v;
                if (outH) outH[(size_t)gr * N + gc] = f2b(v);
            }
        }
}

// ---------------------------------------------------------------------------
// Prep kernels
// ---------------------------------------------------------------------------
__global__ __launch_bounds__(256) void cast_kernel(const float* __restrict__ a,
                                                   ushortT* __restrict__ b, int n) {
    const int i = blockIdx.x * 256 + threadIdx.x;
    if (i < n) b[i] = f2b(a[i]);
}
__global__ __launch_bounds__(256) void gatT_kernel(const float* __restrict__ gW,
                                                   ushortT* __restrict__ gB) {
    const int idx = blockIdx.x * 256 + threadIdx.x; // < 1024*768
    const int c = idx / ND, d = idx - c * ND;
    gB[idx] = f2b(gW[(size_t)d * (NHD * NC) + c]);
}
__global__ __launch_bounds__(256) void upwT_kernel(const float* __restrict__ upW,
                                                   ushortT* __restrict__ o) {
    const int idx = blockIdx.x * 256 + threadIdx.x; // < 256*768
    const int k = idx / ND, d = idx - k * ND;
    o[idx] = f2b(upW[(size_t)d * NC + k]);
}
__global__ __launch_bounds__(256) void bcomb_kernel(const float* __restrict__ gW,
                                                    const float* __restrict__ up_b,
                                                    float* __restrict__ bc) {
    const int c = blockIdx.x * 256 + threadIdx.x;
    if (c >= NHD * NC) return;
    float a = 0.f;
    for (int d = 0; d < ND; ++d) a += up_b[d] * gW[(size_t)d * (NHD * NC) + c];
    bc[c] = a;
}
__global__ __launch_bounds__(256) void spwc_kernel(const float* __restrict__ spW,
                                                   float* __restrict__ o) {
    const int idx = blockIdx.x * 256 + threadIdx.x; // < 768*768
    const int r = idx / ND, d = idx - r * ND;
    o[idx] = spW[(size_t)r * (2 * ND) + d] + spW[(size_t)r * (2 * ND) + ND + d];
}
__global__ __launch_bounds__(256) void wus_kernel(const float* __restrict__ spWc,
                                                  const float* __restrict__ upW,
                                                  ushortT* __restrict__ WusB) {
    const int c = threadIdx.x;
    const int o0 = blockIdx.x * 16;
    float acc[16];
#pragma unroll
    for (int i = 0; i < 16; ++i) acc[i] = 0.f;
    for (int d = 0; d < ND; ++d) {
        const float u = upW[(size_t)d * NC + c];
#pragma unroll
        for (int i = 0; i < 16; ++i) acc[i] += spWc[(size_t)(o0 + i) * ND + d] * u;
    }
#pragma unroll
    for (int i = 0; i < 16; ++i) WusB[(size_t)(o0 + i) * NC + c] = f2b(acc[i]);
}
__global__ __launch_bounds__(256) void bus_kernel(const float* __restrict__ spWc,
                                                  const float* __restrict__ up_b,
                                                  const float* __restrict__ sp_b,
                                                  float* __restrict__ bus) {
    const int o = blockIdx.x * 256 + threadIdx.x;
    if (o >= ND) return;
    float a = sp_b[o];
    const float* sr = spWc + (size_t)o * ND;
    for (int d = 0; d < ND; ++d) a += sr[d] * up_b[d];
    bus[o] = a;
}
__global__ __launch_bounds__(256) void x0_kernel(const float* __restrict__ x,
                                                 ushortT* __restrict__ xb) {
    const int idx = blockIdx.x * 256 + threadIdx.x; // < 2048*768
    const int row = idx / ND, d = idx - row * ND;
    const int g = row >> 4, p = row & 15;
    xb[idx] = f2b(x[((size_t)g * (NS * NP) + p) * ND + d]);
}
__global__ __launch_bounds__(256) void zh_kernel(float* hF, ushortT* hB) {
    const int idx = blockIdx.x * 256 + threadIdx.x; // < 2048*256
    hF[idx] = 0.f;
    hB[idx] = 0;
}

// ---------------------------------------------------------------------------
extern "C" void kernel_launch(void* const* d_in, const int* in_sizes, int n_in,
                              void* d_out, int out_size, void* d_ws, size_t ws_size,
                              hipStream_t stream) {
    (void)in_sizes; (void)n_in; (void)out_size; (void)ws_size;
    const float* x       = (const float*)d_in[0];
    const float* gat_W   = (const float*)d_in[1];
    const float* att_src = (const float*)d_in[2];
    const float* att_dst = (const float*)d_in[3];
    const float* gat_b   = (const float*)d_in[4];
    const float* gru_Wih = (const float*)d_in[5];
    const float* gru_Whh = (const float*)d_in[6];
    const float* gru_bih = (const float*)d_in[7];
    const float* gru_bhh = (const float*)d_in[8];
    const float* up_W    = (const float*)d_in[9];
    const float* up_b    = (const float*)d_in[10];
    const float* sp_W    = (const float*)d_in[11];
    const float* sp_b    = (const float*)d_in[12];
    const float* att_W   = (const float*)d_in[13];
    const float* att_b   = (const float*)d_in[14];
    const float* cls_W   = (const float*)d_in[15];
    const float* cls_b   = (const float*)d_in[16];
    float* outp = (float*)d_out;

    char* w = (char*)d_ws;
    ushortT* xb    = (ushortT*)w; w += (size_t)NR * ND * 2;
    ushortT* WihB  = (ushortT*)w; w += (size_t)(3 * NC) * NC * 2;
    ushortT* WhhB  = (ushortT*)w; w += (size_t)(3 * NC) * NC * 2;
    ushortT* gatB  = (ushortT*)w; w += (size_t)(NHD * NC) * ND * 2;
    ushortT* upWT  = (ushortT*)w; w += (size_t)NC * ND * 2;
    ushortT* WcombB= (ushortT*)w; w += (size_t)(NHD * NC) * NC * 2;
    ushortT* WusB  = (ushortT*)w; w += (size_t)ND * NC * 2;
    float*   bcomb = (float*)w;   w += (size_t)(NHD * NC) * 4;
    float*   spWc  = (float*)w;   w += (size_t)ND * ND * 4;
    float*   bus   = (float*)w;   w += (size_t)ND * 4;
    float*   hF    = (float*)w;   w += (size_t)NR * NC * 4;
    ushortT* hB    = (ushortT*)w; w += (size_t)NR * NC * 2;
    ushortT* hnB   = (ushortT*)w; w += (size_t)NR * NC * 2;
    ushortT* spkB  = (ushortT*)w; w += (size_t)NG * ND * 2;
    float*   hbuf  = (float*)w;   w += (size_t)NR * (NHD * NC) * 4;
    ushortT* mB    = (ushortT*)w; w += (size_t)NR * NC * 2;

    // ---- weight prep ----
    cast_kernel<<<768, 256, 0, stream>>>(gru_Wih, WihB, 3 * NC * NC);
    cast_kernel<<<768, 256, 0, stream>>>(gru_Whh, WhhB, 3 * NC * NC);
    gatT_kernel<<<(NHD * NC * ND) / 256, 256, 0, stream>>>(gat_W, gatB);
    upwT_kernel<<<(NC * ND) / 256, 256, 0, stream>>>(up_W, upWT);
    bcomb_kernel<<<(NHD * NC) / 256, 256, 0, stream>>>(gat_W, up_b, bcomb);
    spwc_kernel<<<(ND * ND) / 256, 256, 0, stream>>>(sp_W, spWc);
    wus_kernel<<<ND / 16, 256, 0, stream>>>(spWc, up_W, WusB);
    bus_kernel<<<3, 256, 0, stream>>>(spWc, up_b, sp_b, bus);
    x0_kernel<<<(NR * ND) / 256, 256, 0, stream>>>(x, xb);
    zh_kernel<<<(NR * NC) / 256, 256, 0, stream>>>(hF, hB);
    // Wcomb[c][k] = sum_d gatW[d][c] * upW[d][k]  -> bf16 Bt layout [1024][256]
    bgemm_kernel<<<dim3(NC / 64, (NHD * NC) / 64), 256, 0, stream>>>(
        gatB, upWT, nullptr, nullptr, WcombB, NC, ND, 0);

    // ---- step 0: hbuf = x0 @ gatW ----
    bgemm_kernel<<<dim3((NHD * NC) / 64, NR / 64), 256, 0, stream>>>(
        xb, gatB, nullptr, hbuf, nullptr, NHD * NC, ND, 0);

    // ---- steps 1..31: two dispatches per step ----
    for (int j = 1; j < NS; ++j) {
        stepA_kernel<<<NG, 512, 0, stream>>>(
            hbuf, hF, hB, hnB, spkB, WihB, WhhB, WusB,
            gru_bih, gru_bhh, bus, att_src, att_dst, gat_b,
            att_W, att_b, cls_W, cls_b, outp, j - 1);
        gatovr_kernel<<<544, 256, 0, stream>>>(
            hnB, spkB, WcombB, gatB, bcomb, hbuf);
    }
    // ---- final fin for s = 31 ----
    fin_kernel<<<NG, 256, 0, stream>>>(hbuf, att_src, att_dst, gat_b,
                                       att_W, att_b, cls_W, cls_b, mB, outp, 31);
}